// Round 10
// baseline (279.822 us; speedup 1.0000x reference)
//
#include <hip/hip_runtime.h>

namespace {
constexpr int NS   = 64;                 // batch
constexpr int NPS  = 802816;             // elements per sample (256*56*56)
constexpr int NPSV = NPS / 4;            // float4 per sample (200704)
constexpr unsigned KSEL = 80281u;        // int(0.1 * 802816)
constexpr unsigned SENT = 0xFFFFFFFFu;
constexpr int NB   = 8192;               // 13-bit prefix bins (u >> 18)
constexpr int GX   = 32;                 // scatter blocks per sample
constexpr int SEGV = NPSV / GX;          // 6272 float4 per scatter block
constexpr int SEG  = NPS / GX;           // 25088 elems per scatter block (fallback seg)
constexpr int PAIRCAP = 1024;            // candidate capacity per scatter block
constexpr int CAP_LDS = 20480;           // per-sample candidate cap for LDS select
constexpr int BRB  = 8;                  // bracket blocks per sample
constexpr int CHUNKS = 128;              // sampled 256-float4 chunks per sample
constexpr int CH_STRIDE = NPSV / CHUNKS; // 1568 float4 between chunk starts
// sample M = 131072 elems; mean rank of k-th = 13109, sigma = 108.6; +/-9 sigma
constexpr unsigned RU_RANK = 12129u;
constexpr unsigned RL_RANK = 14086u;
constexpr int GXA  = 64;                 // fallback apply blocks per sample
constexpr int SEGCAP2 = 20736;           // tier-2 per-block value capacity
constexpr int TAILF4  = 1056;            // tier-2 tail float4 reserved for smalls
constexpr int NBUF = 5;                  // LDS ring slots per wave (depth 4 + 1)
constexpr int KITER = 24;                // 24 pipelined tiles of 256 float4 per block
}

// async global->LDS, 16B per lane; dst is wave-uniform base (+lane*16 by HW)
__device__ __forceinline__ void gload_lds16(const float4* gsrc, float4* ldst) {
    __builtin_amdgcn_global_load_lds(
        (const __attribute__((address_space(1))) unsigned int*)gsrc,
        (__attribute__((address_space(3))) unsigned int*)ldst, 16, 0, 0);
}

// Find bin B (descending) with suffix(B) < K <= suffix(B)+h[B]. SENT if total < K.
// Results are register-latched before the final barrier so back-to-back calls are safe.
template <int NBINS>
__device__ void select_in_lds(const unsigned* __restrict__ h, unsigned K,
                              unsigned* bin, unsigned* rem) {
    constexpr int BPT = NBINS / 256;
    __shared__ unsigned cs[256];
    __shared__ unsigned fB, fR;
    const int t = threadIdx.x;
    unsigned s = 0;
    for (int j = 0; j < BPT; ++j) s += h[t * BPT + j];
    cs[t] = s;
    if (t == 0) { fB = SENT; fR = 0u; }
    __syncthreads();
    unsigned suf = 0;
    for (int j = t + 1; j < 256; ++j) suf += cs[j];
    if (suf < K && suf + s >= K) {
        unsigned cur = suf;
        for (int j = BPT - 1; j >= 0; --j) {
            const unsigned c = h[t * BPT + j];
            if (cur < K && cur + c >= K) { fB = (unsigned)(t * BPT + j); fR = K - cur; break; }
            cur += c;
        }
    }
    __syncthreads();
    const unsigned rb = fB, rr = fR;
    __syncthreads();
    *bin = rb; *rem = rr;
}

// ---- bracket: chunk-sampled 13-bit histogram, 8 blocks/sample -> u16 partials ----
__global__ __launch_bounds__(256) void bracket_kernel(const float4* __restrict__ f,
                                                      const float4* __restrict__ g,
                                                      unsigned short* __restrict__ bh,
                                                      unsigned* __restrict__ fail) {
    __shared__ unsigned h[NB];
    const int jb = blockIdx.x, b = blockIdx.y, t = threadIdx.x;
    if (jb == 0 && b == 0 && t == 0) fail[0] = 0u;
    for (int k = t; k < NB; k += 256) h[k] = 0u;
    __syncthreads();
    const size_t base = (size_t)b * NPSV;
#define HBIN(p) { if ((p) > 0.0f) atomicAdd(&h[__float_as_uint(p) >> 18], 1u); }
    for (int c = 0; c < CHUNKS / BRB; c += 2) {          // 2-chunk unroll: 4 loads in flight
        const int ch = jb * (CHUNKS / BRB) + c;
        const size_t i0 = base + (size_t)ch * CH_STRIDE + t;
        const size_t i1 = base + (size_t)(ch + 1) * CH_STRIDE + t;
        const float4 fa = f[i0], fb = f[i1];
        const float4 ga = g[i0], gb = g[i1];
        HBIN(fa.x * ga.x) HBIN(fa.y * ga.y) HBIN(fa.z * ga.z) HBIN(fa.w * ga.w)
        HBIN(fb.x * gb.x) HBIN(fb.y * gb.y) HBIN(fb.z * gb.z) HBIN(fb.w * gb.w)
    }
#undef HBIN
    __syncthreads();
    unsigned short* o = bh + (size_t)(b * BRB + jb) * NB;
    for (int k = t; k < NB; k += 256) o[k] = (unsigned short)h[k];  // <=16384, fits u16
}

__global__ __launch_bounds__(256) void bracket_scan_kernel(const unsigned short* __restrict__ bh,
                                                           unsigned* __restrict__ binLU) {
    __shared__ unsigned h[NB];
    const int b = blockIdx.x, t = threadIdx.x;
    for (int k = t; k < NB; k += 256) {
        unsigned s = 0;
        const unsigned short* p = bh + (size_t)b * BRB * NB + k;
        for (int j = 0; j < BRB; ++j) s += p[(size_t)j * NB];
        h[k] = s;
    }
    __syncthreads();
    unsigned bU, rU, bL, rL;
    select_in_lds<NB>(h, RU_RANK, &bU, &rU);
    select_in_lds<NB>(h, RL_RANK, &bL, &rL);
    if (t == 0) {
        binLU[2 * b]     = (bL == SENT) ? 0u : bL;
        binLU[2 * b + 1] = (bU == SENT) ? (unsigned)(NB - 1) : bU;
    }
}

// ---- scatter0: per-wave global_load_lds pipeline (depth 4, 5-slot ring), counted
//      vmcnt; candidate appends staged in LDS, flushed coalesced at block end ----
__global__ __launch_bounds__(256) void scatter0_kernel(const float4* __restrict__ f,
                                                       const float4* __restrict__ g,
                                                       float4* __restrict__ out,
                                                       unsigned* __restrict__ pv,
                                                       unsigned* __restrict__ ppos,
                                                       const unsigned* __restrict__ binLU,
                                                       unsigned* __restrict__ cnts,
                                                       unsigned* __restrict__ chis,
                                                       unsigned* __restrict__ fail) {
    const int j = blockIdx.x, b = blockIdx.y, t = threadIdx.x;
    const int wid = t >> 6, lane = t & 63;
    const unsigned binL = binLU[2 * b], binU = binLU[2 * b + 1];
    __shared__ float4 ldsF[4][NBUF][64];
    __shared__ float4 ldsG[4][NBUF][64];
    __shared__ unsigned cnt;
    __shared__ unsigned wsum[4];
    __shared__ unsigned lv[PAIRCAP];
    __shared__ unsigned lp[PAIRCAP];
    if (t == 0) cnt = 0u;
    __syncthreads();
    const size_t base = (size_t)b * NPSV + (size_t)j * SEGV;
    unsigned chi = 0;
#define PROC(FC, GC, IDX, CIDX, OC) { \
        const float p_ = (FC) * (GC); \
        const unsigned u_ = __float_as_uint(p_); \
        const unsigned pre_ = u_ >> 18; \
        const bool pos_ = p_ > 0.0f; \
        const bool drop_ = pos_ && (pre_ > binU); \
        OC = drop_ ? 0.0f : (FC); \
        chi += drop_; \
        if (pos_ && pre_ >= binL && pre_ <= binU) { \
            const unsigned x_ = atomicAdd(&cnt, 1u); \
            if (x_ < PAIRCAP) { lv[x_] = u_; lp[x_] = (unsigned)((IDX) * 4) + CIDX; } \
        } }
#define PROC4(FV, GV, IDX, OV) \
        PROC(FV.x, GV.x, IDX, 0u, OV.x) PROC(FV.y, GV.y, IDX, 1u, OV.y) \
        PROC(FV.z, GV.z, IDX, 2u, OV.z) PROC(FV.w, GV.w, IDX, 3u, OV.w)

#define BODY(K, PREFETCH) { \
        const int slot_ = (K) % NBUF; \
        const float4 fv = ldsF[wid][slot_][lane]; \
        const float4 gv = ldsG[wid][slot_][lane]; \
        if (PREFETCH) { \
            const int kp_ = (K) + 4, sp_ = kp_ % NBUF; \
            gload_lds16(&f[base + kp_ * 256 + t], &ldsF[wid][sp_][0]); \
            gload_lds16(&g[base + kp_ * 256 + t], &ldsG[wid][sp_][0]); \
        } \
        float4 o; \
        PROC4(fv, gv, j * SEGV + (K) * 256 + t, o) \
        out[base + (K) * 256 + t] = o; }

    // prologue: stage tiles 0..3 (8 gloads in flight per wave)
#pragma unroll
    for (int k = 0; k < 4; ++k) {
        gload_lds16(&f[base + k * 256 + t], &ldsF[wid][k][0]);
        gload_lds16(&g[base + k * 256 + t], &ldsG[wid][k][0]);
    }
    // warm-up: tile k needs all prologue gloads up to it; <=6 younger ops outstanding ok
    for (int k = 0; k < 4; ++k) {
        asm volatile("s_waitcnt vmcnt(6)" ::: "memory");
        __builtin_amdgcn_sched_barrier(0);
        BODY(k, 1)
    }
    // steady state: younger = 6 gloads + 4 stores = 10
    for (int k = 4; k < KITER - 4; ++k) {
        asm volatile("s_waitcnt vmcnt(10)" ::: "memory");
        __builtin_amdgcn_sched_barrier(0);
        BODY(k, 1)
    }
    // drain, then last 4 tiles straight from LDS
    asm volatile("s_waitcnt vmcnt(0)" ::: "memory");
    __builtin_amdgcn_sched_barrier(0);
    for (int k = KITER - 4; k < KITER; ++k) {
        BODY(k, 0)
    }
    {   // tail: SEGV - KITER*256 = 128 float4, plain path
        if (t < SEGV - KITER * 256) {
            const int i = KITER * 256 + t;
            const float4 fv = f[base + i];
            const float4 gv = g[base + i];
            float4 o;
            PROC4(fv, gv, j * SEGV + i, o)
            out[base + i] = o;
        }
    }
#undef BODY
#undef PROC4
#undef PROC
    // block-reduce chi
    for (int off = 32; off; off >>= 1) chi += __shfl_down(chi, off);
    if ((t & 63) == 0) wsum[t >> 6] = chi;
    __syncthreads();
    // coalesced flush of the candidate staging
    const unsigned ctot = cnt;
    const unsigned c = (ctot > PAIRCAP) ? PAIRCAP : ctot;
    const size_t segp = (size_t)(b * GX + j) * PAIRCAP;
    for (unsigned k = t; k < c; k += 256) { pv[segp + k] = lv[k]; ppos[segp + k] = lp[k]; }
    if (t == 0) {
        chis[b * GX + j] = wsum[0] + wsum[1] + wsum[2] + wsum[3];
        cnts[b * GX + j] = c;
        if (ctot > PAIRCAP) fail[0] = 1u;   // overflow -> exact fallback
    }
}

// ---- select0+fixup: LDS-resident exact 3-level radix select, then zero the
//      candidate positions above the threshold (vals already in LDS) ----
__global__ __launch_bounds__(256) void select0_kernel(const unsigned* __restrict__ pv,
                                                      const unsigned* __restrict__ ppos,
                                                      const unsigned* __restrict__ binLU,
                                                      const unsigned* __restrict__ cnts,
                                                      const unsigned* __restrict__ chis,
                                                      unsigned* __restrict__ fail,
                                                      float* __restrict__ thrF,
                                                      float* __restrict__ out) {
    if (fail[0]) return;
    const int b = blockIdx.x, t = threadIdx.x;
    __shared__ unsigned vals[CAP_LDS];
    __shared__ unsigned hist[NB];
    __shared__ unsigned soff[GX + 1];
    __shared__ unsigned sh_chi;
    __shared__ float sh_thr;
    if (t == 0) {
        unsigned o = 0;
        for (int j = 0; j < GX; ++j) { soff[j] = o; o += cnts[b * GX + j]; }
        soff[GX] = o;
        unsigned c = 0;
        for (int j = 0; j < GX; ++j) c += chis[b * GX + j];
        sh_chi = c;
    }
    __syncthreads();
    const unsigned ncand = soff[GX];
    const unsigned chi = sh_chi;
    if (chi >= KSEL) { if (t == 0) fail[0] = 1u; return; }      // k-th above bracket
    if (ncand > CAP_LDS) { if (t == 0) fail[0] = 1u; return; }
    const unsigned Krem = KSEL - chi;
    bool zeroThr = false;
    if (Krem > ncand) {
        if (binLU[2 * b] == 0u) zeroThr = true;                 // < k positives: thr = 0
        else { if (t == 0) fail[0] = 1u; return; }              // k-th below bracket
    }
    // load candidates into LDS
    for (int j = 0; j < GX; ++j) {
        const unsigned c = soff[j + 1] - soff[j];
        const unsigned* s = pv + (size_t)(b * GX + j) * PAIRCAP;
        for (unsigned i = t; i < c; i += 256) vals[soff[j] + i] = s[i];
    }
    if (zeroThr) {
        if (t == 0) { sh_thr = 0.0f; thrF[b] = 0.0f; }
        __syncthreads();
    } else {
        // sweep 1: bits 30..18
        for (int k = t; k < NB; k += 256) hist[k] = 0u;
        __syncthreads();
        for (unsigned i = t; i < ncand; i += 256) atomicAdd(&hist[vals[i] >> 18], 1u);
        __syncthreads();
        unsigned P1, r1; select_in_lds<NB>(hist, Krem, &P1, &r1);
        __syncthreads();
        // sweep 2: bits 17..5
        for (int k = t; k < NB; k += 256) hist[k] = 0u;
        __syncthreads();
        for (unsigned i = t; i < ncand; i += 256) {
            const unsigned u = vals[i];
            if ((u >> 18) == P1) atomicAdd(&hist[(u >> 5) & (NB - 1u)], 1u);
        }
        __syncthreads();
        unsigned P2, r2; select_in_lds<NB>(hist, r1, &P2, &r2);
        __syncthreads();
        // sweep 3: bits 4..0
        if (t < 32) hist[t] = 0u;
        __syncthreads();
        const unsigned pref = (P1 << 13) | P2;
        for (unsigned i = t; i < ncand; i += 256) {
            const unsigned u = vals[i];
            if ((u >> 5) == pref) atomicAdd(&hist[u & 31u], 1u);
        }
        __syncthreads();
        if (t == 0) {
            unsigned cur = 0, b3 = 0;
            for (int q = 31; q >= 0; --q) {
                const unsigned c = hist[q];
                if (cur < r2 && cur + c >= r2) { b3 = (unsigned)q; break; }
                cur += c;
            }
            const float thr = __uint_as_float((P1 << 18) | (P2 << 5) | b3);
            sh_thr = thr; thrF[b] = thr;
        }
        __syncthreads();
    }
    // fixup: zero candidate positions whose value exceeds thr
    const float thr = sh_thr;
    float* ob = out + (size_t)b * NPS;
    for (int j = 0; j < GX; ++j) {
        const unsigned c = soff[j + 1] - soff[j];
        const unsigned* qp = ppos + (size_t)(b * GX + j) * PAIRCAP;
        const unsigned so = soff[j];
        for (unsigned i = t; i < c; i += 256) {
            if (__uint_as_float(vals[so + i]) > thr) ob[qp[i]] = 0.0f;
        }
    }
}

// ================= exact fallback path (mode1: predicated on fail; mode2: tier-2) ======
__global__ __launch_bounds__(256) void scatter_fb_kernel(const float4* __restrict__ f,
                                                         const float4* __restrict__ g,
                                                         unsigned* __restrict__ list,
                                                         unsigned* __restrict__ cnts,
                                                         unsigned* __restrict__ chis,
                                                         const unsigned* __restrict__ fail,
                                                         int mode, int segCap) {
    if (mode == 1 && fail[0] == 0u) return;
    const int j = blockIdx.x, b = blockIdx.y, t = threadIdx.x;
    __shared__ unsigned cnt;
    if (t == 0) cnt = 0u;
    __syncthreads();
    unsigned* __restrict__ seg = list + (size_t)b * NPS + (size_t)j * SEG;
    const size_t base = (size_t)b * NPSV + (size_t)j * SEGV;
    for (int i = t; i < SEGV; i += 256) {
        const float4 fv = f[base + i];
        const float4 gv = g[base + i];
        const float p0 = fv.x * gv.x, p1 = fv.y * gv.y, p2 = fv.z * gv.z, p3 = fv.w * gv.w;
#define PROCF(p) { if ((p) > 0.0f) { const unsigned x = atomicAdd(&cnt, 1u); \
                   if ((int)x < segCap) seg[x] = __float_as_uint(p); } }
        PROCF(p0) PROCF(p1) PROCF(p2) PROCF(p3)
#undef PROCF
    }
    __syncthreads();
    if (t == 0) {
        cnts[b * GX + j] = (cnt > (unsigned)segCap) ? (unsigned)segCap : cnt;
        chis[b * GX + j] = 0u;
    }
}

__global__ __launch_bounds__(256) void select_fb_kernel(const unsigned* __restrict__ list,
                                                        const unsigned* __restrict__ cnts,
                                                        unsigned* __restrict__ fail,
                                                        float* __restrict__ thrF,
                                                        int mode) {
    if (mode == 1 && fail[0] == 0u) return;
    const int b = blockIdx.x, t = threadIdx.x;
    __shared__ unsigned h[NB];
    __shared__ unsigned segc[GX];
    if (t < GX) segc[t] = cnts[b * GX + t];
    __syncthreads();
    unsigned ncand = 0;
    for (int j = 0; j < GX; ++j) ncand += segc[j];
    if (KSEL > ncand) {              // fewer than k positives: threshold 0 (exact)
        if (t == 0) thrF[b] = 0.0f;
        return;
    }
    const unsigned* __restrict__ seg0 = list + (size_t)b * NPS;
    // sweep 1: bits 30..18
    for (int k = t; k < NB; k += 256) h[k] = 0u;
    __syncthreads();
    for (int j = 0; j < GX; ++j) {
        const unsigned c = segc[j];
        const unsigned* s = seg0 + (size_t)j * SEG;
        for (unsigned i = t; i < c; i += 256) atomicAdd(&h[s[i] >> 18], 1u);
    }
    __syncthreads();
    unsigned P1, r1; select_in_lds<NB>(h, KSEL, &P1, &r1);
    __syncthreads();
    // sweep 2: bits 17..5
    for (int k = t; k < NB; k += 256) h[k] = 0u;
    __syncthreads();
    for (int j = 0; j < GX; ++j) {
        const unsigned c = segc[j];
        const unsigned* s = seg0 + (size_t)j * SEG;
        for (unsigned i = t; i < c; i += 256) {
            const unsigned u = s[i];
            if ((u >> 18) == P1) atomicAdd(&h[(u >> 5) & (NB - 1u)], 1u);
        }
    }
    __syncthreads();
    unsigned P2, r2; select_in_lds<NB>(h, r1, &P2, &r2);
    __syncthreads();
    // sweep 3: bits 4..0
    if (t < 32) h[t] = 0u;
    __syncthreads();
    const unsigned pref = (P1 << 13) | P2;
    for (int j = 0; j < GX; ++j) {
        const unsigned c = segc[j];
        const unsigned* s = seg0 + (size_t)j * SEG;
        for (unsigned i = t; i < c; i += 256) {
            const unsigned u = s[i];
            if ((u >> 5) == pref) atomicAdd(&h[u & 31u], 1u);
        }
    }
    __syncthreads();
    if (t == 0) {
        unsigned cur = 0, b3 = 0;
        for (int q = 31; q >= 0; --q) {
            const unsigned c = h[q];
            if (cur < r2 && cur + c >= r2) { b3 = (unsigned)q; break; }
            cur += c;
        }
        thrF[b] = __uint_as_float((P1 << 18) | (P2 << 5) | b3);
    }
}

__global__ __launch_bounds__(256) void apply_fb_kernel(const float4* __restrict__ f,
                                                       const float4* __restrict__ g,
                                                       const float* __restrict__ thrF,
                                                       float4* __restrict__ out,
                                                       const unsigned* __restrict__ fail,
                                                       int mode, int tailCut) {
    if (mode == 1 && fail[0] == 0u) return;
    const int b = blockIdx.y;
    const float thr = thrF[b];
    const size_t base = (size_t)b * NPSV;
    const int limit = NPSV - ((b == NS - 1) ? tailCut : 0);
    const int stride = gridDim.x * blockDim.x;
    for (int i = blockIdx.x * 256 + threadIdx.x; i < limit; i += stride) {
        const float4 fv = f[base + i];
        const float4 gv = g[base + i];
        float4 o;
        o.x = (fv.x * gv.x > thr) ? 0.0f : fv.x;
        o.y = (fv.y * gv.y > thr) ? 0.0f : fv.y;
        o.z = (fv.z * gv.z > thr) ? 0.0f : fv.z;
        o.w = (fv.w * gv.w > thr) ? 0.0f : fv.w;
        out[base + i] = o;
    }
}

__global__ void apply_tail_kernel(const float4* __restrict__ f, const float4* __restrict__ g,
                                  const float* __restrict__ thrF,
                                  float4* __restrict__ out, int tailCut) {
    const float thr = thrF[NS - 1];
    asm volatile("" :: "v"(thr));   // latch before overwriting the smalls region
    __syncthreads();
    const size_t base = (size_t)NS * NPSV - tailCut;
    for (int i = threadIdx.x; i < tailCut; i += 256) {
        const float4 fv = f[base + i];
        const float4 gv = g[base + i];
        float4 o;
        o.x = (fv.x * gv.x > thr) ? 0.0f : fv.x;
        o.y = (fv.y * gv.y > thr) ? 0.0f : fv.y;
        o.z = (fv.z * gv.z > thr) ? 0.0f : fv.z;
        o.w = (fv.w * gv.w > thr) ? 0.0f : fv.w;
        out[base + i] = o;
    }
}

extern "C" void kernel_launch(void* const* d_in, const int* in_sizes, int n_in,
                              void* d_out, int out_size, void* d_ws, size_t ws_size,
                              hipStream_t stream) {
    const float* f = (const float*)d_in[0];
    const float* g = (const float*)d_in[1];
    float* out = (float*)d_out;

    const size_t pairU32  = (size_t)NS * GX * PAIRCAP;                 // 2,097,152
    const size_t brBytes  = (size_t)NS * BRB * NB * sizeof(unsigned short);  // 8 MB
    const size_t bigBytes = (pairU32 * 8 > brBytes) ? pairU32 * 8 : brBytes; // 16.78 MB
    const size_t smallU32 = 2 * NS + NS * GX + NS * GX + 1 + NS;
    const size_t need     = bigBytes + smallU32 * 4;

    if (ws_size >= need) {
        // ---- tier-1 fast path: bracket hists and pairs share (time-disjoint) ws ----
        char* w = (char*)d_ws;
        unsigned short* bh = (unsigned short*)w;
        unsigned* pv   = (unsigned*)w;
        unsigned* ppos = pv + pairU32;
        unsigned* sm   = (unsigned*)(w + bigBytes);
        unsigned* binLU = sm;                 // 128
        unsigned* cnts  = binLU + 2 * NS;     // 2048
        unsigned* chis  = cnts + NS * GX;     // 2048
        unsigned* fail  = chis + NS * GX;     // 1
        float*    thrF  = (float*)(fail + 1); // 64

        bracket_kernel<<<dim3(BRB, NS), 256, 0, stream>>>((const float4*)f, (const float4*)g,
                                                          bh, fail);
        bracket_scan_kernel<<<NS, 256, 0, stream>>>(bh, binLU);
        scatter0_kernel<<<dim3(GX, NS), 256, 0, stream>>>((const float4*)f, (const float4*)g,
                                                          (float4*)out, pv, ppos, binLU,
                                                          cnts, chis, fail);
        select0_kernel<<<NS, 256, 0, stream>>>(pv, ppos, binLU, cnts, chis, fail, thrF, out);
        // guaranteed-exact fallback; all three no-op unless fail was set
        scatter_fb_kernel<<<dim3(GX, NS), 256, 0, stream>>>((const float4*)f, (const float4*)g,
                                                            (unsigned*)out, cnts, chis, fail,
                                                            1, SEG);
        select_fb_kernel<<<NS, 256, 0, stream>>>((const unsigned*)out, cnts, fail, thrF, 1);
        apply_fb_kernel<<<dim3(GXA, NS), 256, 0, stream>>>((const float4*)f, (const float4*)g,
                                                           thrF, (float4*)out, fail, 1, 0);
    } else {
        // ---- tier-2: no usable ws; everything lives in d_out (always exact for this
        // data: per-block positives ~12.5K << SEGCAP2) ----
        unsigned* list = (unsigned*)out;
        unsigned* sm   = (unsigned*)out + ((size_t)NS * NPS - 4 * TAILF4);
        unsigned* cnts = sm;
        unsigned* chis = cnts + NS * GX;
        unsigned* fail = chis + NS * GX;
        float*    thrF = (float*)(fail + 1);

        scatter_fb_kernel<<<dim3(GX, NS), 256, 0, stream>>>((const float4*)f, (const float4*)g,
                                                            list, cnts, chis, fail, 2, SEGCAP2);
        select_fb_kernel<<<NS, 256, 0, stream>>>(list, cnts, fail, thrF, 2);
        apply_fb_kernel<<<dim3(GXA, NS), 256, 0, stream>>>((const float4*)f, (const float4*)g,
                                                           thrF, (float4*)out, fail, 2, TAILF4);
        apply_tail_kernel<<<1, 256, 0, stream>>>((const float4*)f, (const float4*)g,
                                                 thrF, (float4*)out, TAILF4);
    }
}

// Round 12
// 219.797 us; speedup vs baseline: 1.2731x; 1.2731x over previous
//
#include <hip/hip_runtime.h>

namespace {
constexpr int NS   = 64;                 // batch
constexpr int NPS  = 802816;             // elements per sample (256*56*56)
constexpr int NPSV = NPS / 4;            // float4 per sample (200704)
constexpr unsigned KSEL = 80281u;        // int(0.1 * 802816)
constexpr unsigned SENT = 0xFFFFFFFFu;
constexpr int NB   = 8192;               // 13-bit prefix bins (u >> 18)
constexpr int GX   = 16;                 // scatter blocks per sample (interleaved tiles)
constexpr int TPB  = 49;                 // tiles per scatter block (784 = 16*49, no tail)
constexpr int PAIRCAP = 2048;            // candidate capacity per scatter block
constexpr int CAP_LDS = 20480;           // per-sample candidate cap for LDS select
constexpr int BRB  = 8;                  // bracket blocks per sample
constexpr int CHUNKS = 128;              // sampled 256-float4 chunks per sample
constexpr int CH_STRIDE = NPSV / CHUNKS; // 1568 float4 between chunk starts
// sample M = 131072 elems; mean rank of k-th = 13109, sigma = 108.6; +/-9 sigma
constexpr unsigned RU_RANK = 12129u;
constexpr unsigned RL_RANK = 14086u;
// fallback partitioning (contiguous segments, proven path)
constexpr int GXF  = 32;
constexpr int SEGVF = NPSV / GXF;        // 6272 float4
constexpr int SEGF  = NPS / GXF;         // 25088 elems
constexpr int GXA  = 64;
constexpr int SEGCAP2 = 20736;           // tier-2 per-block value capacity
constexpr int TAILF4  = 1056;            // tier-2 tail float4 reserved for smalls
typedef float f32x4 __attribute__((ext_vector_type(4)));
}

__device__ __forceinline__ void nt_store4(float4* dst, const float4& v) {
    f32x4 w; w.x = v.x; w.y = v.y; w.z = v.z; w.w = v.w;
    __builtin_nontemporal_store(w, reinterpret_cast<f32x4*>(dst));
}

// Find bin B (descending) with suffix(B) < K <= suffix(B)+h[B]. SENT if total < K.
// Results are register-latched before the final barrier so back-to-back calls are safe.
template <int NBINS>
__device__ void select_in_lds(const unsigned* __restrict__ h, unsigned K,
                              unsigned* bin, unsigned* rem) {
    constexpr int BPT = NBINS / 256;
    __shared__ unsigned cs[256];
    __shared__ unsigned fB, fR;
    const int t = threadIdx.x;
    unsigned s = 0;
    for (int j = 0; j < BPT; ++j) s += h[t * BPT + j];
    cs[t] = s;
    if (t == 0) { fB = SENT; fR = 0u; }
    __syncthreads();
    unsigned suf = 0;
    for (int j = t + 1; j < 256; ++j) suf += cs[j];
    if (suf < K && suf + s >= K) {
        unsigned cur = suf;
        for (int j = BPT - 1; j >= 0; --j) {
            const unsigned c = h[t * BPT + j];
            if (cur < K && cur + c >= K) { fB = (unsigned)(t * BPT + j); fR = K - cur; break; }
            cur += c;
        }
    }
    __syncthreads();
    const unsigned rb = fB, rr = fR;
    __syncthreads();
    *bin = rb; *rem = rr;
}

// ---- bracket: chunk-sampled 13-bit histogram, 8 blocks/sample -> u16 partials ----
__global__ __launch_bounds__(256) void bracket_kernel(const float4* __restrict__ f,
                                                      const float4* __restrict__ g,
                                                      unsigned short* __restrict__ bh,
                                                      unsigned* __restrict__ fail) {
    __shared__ unsigned h[NB];
    const int jb = blockIdx.x, b = blockIdx.y, t = threadIdx.x;
    if (jb == 0 && b == 0 && t == 0) fail[0] = 0u;
    for (int k = t; k < NB; k += 256) h[k] = 0u;
    __syncthreads();
    const size_t base = (size_t)b * NPSV;
#define HBIN(p) { if ((p) > 0.0f) atomicAdd(&h[__float_as_uint(p) >> 18], 1u); }
    for (int c = 0; c < CHUNKS / BRB; c += 2) {          // 2-chunk unroll: 4 loads in flight
        const int ch = jb * (CHUNKS / BRB) + c;
        const size_t i0 = base + (size_t)ch * CH_STRIDE + t;
        const size_t i1 = base + (size_t)(ch + 1) * CH_STRIDE + t;
        const float4 fa = f[i0], fb = f[i1];
        const float4 ga = g[i0], gb = g[i1];
        HBIN(fa.x * ga.x) HBIN(fa.y * ga.y) HBIN(fa.z * ga.z) HBIN(fa.w * ga.w)
        HBIN(fb.x * gb.x) HBIN(fb.y * gb.y) HBIN(fb.z * gb.z) HBIN(fb.w * gb.w)
    }
#undef HBIN
    __syncthreads();
    unsigned short* o = bh + (size_t)(b * BRB + jb) * NB;
    for (int k = t; k < NB; k += 256) o[k] = (unsigned short)h[k];  // <=16384, fits u16
}

__global__ __launch_bounds__(256) void bracket_scan_kernel(const unsigned short* __restrict__ bh,
                                                           unsigned* __restrict__ binLU) {
    __shared__ unsigned h[NB];
    const int b = blockIdx.x, t = threadIdx.x;
    for (int k = t; k < NB; k += 256) {
        unsigned s = 0;
        const unsigned short* p = bh + (size_t)b * BRB * NB + k;
        for (int j = 0; j < BRB; ++j) s += p[(size_t)j * NB];
        h[k] = s;
    }
    __syncthreads();
    unsigned bU, rU, bL, rL;
    select_in_lds<NB>(h, RU_RANK, &bU, &rU);
    select_in_lds<NB>(h, RL_RANK, &bL, &rL);
    if (t == 0) {
        binLU[2 * b]     = (bL == SENT) ? 0u : bL;
        binLU[2 * b + 1] = (bU == SENT) ? (unsigned)(NB - 1) : bU;
    }
}

// ---- scatter0: INTERLEAVED tile mapping — the GX blocks of a sample advance one
//      coherent 64KB front per stream (block j owns tiles j, j+GX, ...). Candidate
//      appends staged in LDS, flushed coalesced at block end. ----
__global__ __launch_bounds__(256) void scatter0_kernel(const float4* __restrict__ f,
                                                       const float4* __restrict__ g,
                                                       float4* __restrict__ out,
                                                       unsigned* __restrict__ pv,
                                                       unsigned* __restrict__ ppos,
                                                       const unsigned* __restrict__ binLU,
                                                       unsigned* __restrict__ cnts,
                                                       unsigned* __restrict__ chis,
                                                       unsigned* __restrict__ fail) {
    const int j = blockIdx.x, b = blockIdx.y, t = threadIdx.x;
    const unsigned binL = binLU[2 * b], binU = binLU[2 * b + 1];
    __shared__ unsigned cnt;
    __shared__ unsigned wsum[4];
    __shared__ unsigned lv[PAIRCAP];
    __shared__ unsigned lp[PAIRCAP];
    if (t == 0) cnt = 0u;
    __syncthreads();
    const size_t sbase = (size_t)b * NPSV;
    unsigned chi = 0;
#define PROC(FC, GC, IDX, CIDX, OC) { \
        const float p_ = (FC) * (GC); \
        const unsigned u_ = __float_as_uint(p_); \
        const unsigned pre_ = u_ >> 18; \
        const bool pos_ = p_ > 0.0f; \
        const bool drop_ = pos_ && (pre_ > binU); \
        OC = drop_ ? 0.0f : (FC); \
        chi += drop_; \
        if (pos_ && pre_ >= binL && pre_ <= binU) { \
            const unsigned x_ = atomicAdd(&cnt, 1u); \
            if (x_ < PAIRCAP) { lv[x_] = u_; lp[x_] = (unsigned)((IDX) * 4) + CIDX; } \
        } }
#define PROC4(FV, GV, IDX, OV) \
        PROC(FV.x, GV.x, IDX, 0u, OV.x) PROC(FV.y, GV.y, IDX, 1u, OV.y) \
        PROC(FV.z, GV.z, IDX, 2u, OV.z) PROC(FV.w, GV.w, IDX, 3u, OV.w)

    for (int k = 0; k < TPB; ++k) {
        const int i = (k * GX + j) * 256 + t;    // f4 index within sample
        const float4 fv = f[sbase + i];
        const float4 gv = g[sbase + i];
        float4 o;
        PROC4(fv, gv, i, o)
        nt_store4(&out[sbase + i], o);
    }
#undef PROC4
#undef PROC
    // block-reduce chi
    for (int off = 32; off; off >>= 1) chi += __shfl_down(chi, off);
    if ((t & 63) == 0) wsum[t >> 6] = chi;
    __syncthreads();
    // coalesced flush of the candidate staging
    const unsigned ctot = cnt;
    const unsigned c = (ctot > PAIRCAP) ? PAIRCAP : ctot;
    const size_t segp = (size_t)(b * GX + j) * PAIRCAP;
    for (unsigned k = t; k < c; k += 256) { pv[segp + k] = lv[k]; ppos[segp + k] = lp[k]; }
    if (t == 0) {
        chis[b * GX + j] = wsum[0] + wsum[1] + wsum[2] + wsum[3];
        cnts[b * GX + j] = c;
        if (ctot > PAIRCAP) fail[0] = 1u;   // overflow -> exact fallback
    }
}

// ---- select0+fixup: LDS-resident exact 3-level radix select, then zero the
//      candidate positions above the threshold (vals already in LDS) ----
__global__ __launch_bounds__(256) void select0_kernel(const unsigned* __restrict__ pv,
                                                      const unsigned* __restrict__ ppos,
                                                      const unsigned* __restrict__ binLU,
                                                      const unsigned* __restrict__ cnts,
                                                      const unsigned* __restrict__ chis,
                                                      unsigned* __restrict__ fail,
                                                      float* __restrict__ thrF,
                                                      float* __restrict__ out) {
    if (fail[0]) return;
    const int b = blockIdx.x, t = threadIdx.x;
    __shared__ unsigned vals[CAP_LDS];
    __shared__ unsigned hist[NB];
    __shared__ unsigned soff[GX + 1];
    __shared__ unsigned sh_chi;
    __shared__ float sh_thr;
    if (t == 0) {
        unsigned o = 0;
        for (int j = 0; j < GX; ++j) { soff[j] = o; o += cnts[b * GX + j]; }
        soff[GX] = o;
        unsigned c = 0;
        for (int j = 0; j < GX; ++j) c += chis[b * GX + j];
        sh_chi = c;
    }
    __syncthreads();
    const unsigned ncand = soff[GX];
    const unsigned chi = sh_chi;
    if (chi >= KSEL) { if (t == 0) fail[0] = 1u; return; }      // k-th above bracket
    if (ncand > CAP_LDS) { if (t == 0) fail[0] = 1u; return; }
    const unsigned Krem = KSEL - chi;
    bool zeroThr = false;
    if (Krem > ncand) {
        if (binLU[2 * b] == 0u) zeroThr = true;                 // < k positives: thr = 0
        else { if (t == 0) fail[0] = 1u; return; }              // k-th below bracket
    }
    // load candidates into LDS
    for (int j = 0; j < GX; ++j) {
        const unsigned c = soff[j + 1] - soff[j];
        const unsigned* s = pv + (size_t)(b * GX + j) * PAIRCAP;
        for (unsigned i = t; i < c; i += 256) vals[soff[j] + i] = s[i];
    }
    if (zeroThr) {
        if (t == 0) { sh_thr = 0.0f; thrF[b] = 0.0f; }
        __syncthreads();
    } else {
        // sweep 1: bits 30..18
        for (int k = t; k < NB; k += 256) hist[k] = 0u;
        __syncthreads();
        for (unsigned i = t; i < ncand; i += 256) atomicAdd(&hist[vals[i] >> 18], 1u);
        __syncthreads();
        unsigned P1, r1; select_in_lds<NB>(hist, Krem, &P1, &r1);
        __syncthreads();
        // sweep 2: bits 17..5
        for (int k = t; k < NB; k += 256) hist[k] = 0u;
        __syncthreads();
        for (unsigned i = t; i < ncand; i += 256) {
            const unsigned u = vals[i];
            if ((u >> 18) == P1) atomicAdd(&hist[(u >> 5) & (NB - 1u)], 1u);
        }
        __syncthreads();
        unsigned P2, r2; select_in_lds<NB>(hist, r1, &P2, &r2);
        __syncthreads();
        // sweep 3: bits 4..0
        if (t < 32) hist[t] = 0u;
        __syncthreads();
        const unsigned pref = (P1 << 13) | P2;
        for (unsigned i = t; i < ncand; i += 256) {
            const unsigned u = vals[i];
            if ((u >> 5) == pref) atomicAdd(&hist[u & 31u], 1u);
        }
        __syncthreads();
        if (t == 0) {
            unsigned cur = 0, b3 = 0;
            for (int q = 31; q >= 0; --q) {
                const unsigned c = hist[q];
                if (cur < r2 && cur + c >= r2) { b3 = (unsigned)q; break; }
                cur += c;
            }
            const float thr = __uint_as_float((P1 << 18) | (P2 << 5) | b3);
            sh_thr = thr; thrF[b] = thr;
        }
        __syncthreads();
    }
    // fixup: zero candidate positions whose value exceeds thr
    const float thr = sh_thr;
    float* ob = out + (size_t)b * NPS;
    for (int j = 0; j < GX; ++j) {
        const unsigned c = soff[j + 1] - soff[j];
        const unsigned* qp = ppos + (size_t)(b * GX + j) * PAIRCAP;
        const unsigned so = soff[j];
        for (unsigned i = t; i < c; i += 256) {
            if (__uint_as_float(vals[so + i]) > thr) ob[qp[i]] = 0.0f;
        }
    }
}

// ================= exact fallback path (mode1: predicated on fail; mode2: tier-2) ======
__global__ __launch_bounds__(256) void scatter_fb_kernel(const float4* __restrict__ f,
                                                         const float4* __restrict__ g,
                                                         unsigned* __restrict__ list,
                                                         unsigned* __restrict__ cnts,
                                                         unsigned* __restrict__ chis,
                                                         const unsigned* __restrict__ fail,
                                                         int mode, int segCap) {
    if (mode == 1 && fail[0] == 0u) return;
    const int j = blockIdx.x, b = blockIdx.y, t = threadIdx.x;
    __shared__ unsigned cnt;
    if (t == 0) cnt = 0u;
    __syncthreads();
    unsigned* __restrict__ seg = list + (size_t)b * NPS + (size_t)j * SEGF;
    const size_t base = (size_t)b * NPSV + (size_t)j * SEGVF;
    for (int i = t; i < SEGVF; i += 256) {
        const float4 fv = f[base + i];
        const float4 gv = g[base + i];
        const float p0 = fv.x * gv.x, p1 = fv.y * gv.y, p2 = fv.z * gv.z, p3 = fv.w * gv.w;
#define PROCF(p) { if ((p) > 0.0f) { const unsigned x = atomicAdd(&cnt, 1u); \
                   if ((int)x < segCap) seg[x] = __float_as_uint(p); } }
        PROCF(p0) PROCF(p1) PROCF(p2) PROCF(p3)
#undef PROCF
    }
    __syncthreads();
    if (t == 0) {
        cnts[b * GXF + j] = (cnt > (unsigned)segCap) ? (unsigned)segCap : cnt;
        chis[b * GXF + j] = 0u;
    }
}

__global__ __launch_bounds__(256) void select_fb_kernel(const unsigned* __restrict__ list,
                                                        const unsigned* __restrict__ cnts,
                                                        unsigned* __restrict__ fail,
                                                        float* __restrict__ thrF,
                                                        int mode) {
    if (mode == 1 && fail[0] == 0u) return;
    const int b = blockIdx.x, t = threadIdx.x;
    __shared__ unsigned h[NB];
    __shared__ unsigned segc[GXF];
    if (t < GXF) segc[t] = cnts[b * GXF + t];
    __syncthreads();
    unsigned ncand = 0;
    for (int j = 0; j < GXF; ++j) ncand += segc[j];
    if (KSEL > ncand) {              // fewer than k positives: threshold 0 (exact)
        if (t == 0) thrF[b] = 0.0f;
        return;
    }
    const unsigned* __restrict__ seg0 = list + (size_t)b * NPS;
    // sweep 1: bits 30..18
    for (int k = t; k < NB; k += 256) h[k] = 0u;
    __syncthreads();
    for (int j = 0; j < GXF; ++j) {
        const unsigned c = segc[j];
        const unsigned* s = seg0 + (size_t)j * SEGF;
        for (unsigned i = t; i < c; i += 256) atomicAdd(&h[s[i] >> 18], 1u);
    }
    __syncthreads();
    unsigned P1, r1; select_in_lds<NB>(h, KSEL, &P1, &r1);
    __syncthreads();
    // sweep 2: bits 17..5
    for (int k = t; k < NB; k += 256) h[k] = 0u;
    __syncthreads();
    for (int j = 0; j < GXF; ++j) {
        const unsigned c = segc[j];
        const unsigned* s = seg0 + (size_t)j * SEGF;
        for (unsigned i = t; i < c; i += 256) {
            const unsigned u = s[i];
            if ((u >> 18) == P1) atomicAdd(&h[(u >> 5) & (NB - 1u)], 1u);
        }
    }
    __syncthreads();
    unsigned P2, r2; select_in_lds<NB>(h, r1, &P2, &r2);
    __syncthreads();
    // sweep 3: bits 4..0
    if (t < 32) h[t] = 0u;
    __syncthreads();
    const unsigned pref = (P1 << 13) | P2;
    for (int j = 0; j < GXF; ++j) {
        const unsigned c = segc[j];
        const unsigned* s = seg0 + (size_t)j * SEGF;
        for (unsigned i = t; i < c; i += 256) {
            const unsigned u = s[i];
            if ((u >> 5) == pref) atomicAdd(&h[u & 31u], 1u);
        }
    }
    __syncthreads();
    if (t == 0) {
        unsigned cur = 0, b3 = 0;
        for (int q = 31; q >= 0; --q) {
            const unsigned c = h[q];
            if (cur < r2 && cur + c >= r2) { b3 = (unsigned)q; break; }
            cur += c;
        }
        thrF[b] = __uint_as_float((P1 << 18) | (P2 << 5) | b3);
    }
}

__global__ __launch_bounds__(256) void apply_fb_kernel(const float4* __restrict__ f,
                                                       const float4* __restrict__ g,
                                                       const float* __restrict__ thrF,
                                                       float4* __restrict__ out,
                                                       const unsigned* __restrict__ fail,
                                                       int mode, int tailCut) {
    if (mode == 1 && fail[0] == 0u) return;
    const int b = blockIdx.y;
    const float thr = thrF[b];
    const size_t base = (size_t)b * NPSV;
    const int limit = NPSV - ((b == NS - 1) ? tailCut : 0);
    const int stride = gridDim.x * blockDim.x;
    for (int i = blockIdx.x * 256 + threadIdx.x; i < limit; i += stride) {
        const float4 fv = f[base + i];
        const float4 gv = g[base + i];
        float4 o;
        o.x = (fv.x * gv.x > thr) ? 0.0f : fv.x;
        o.y = (fv.y * gv.y > thr) ? 0.0f : fv.y;
        o.z = (fv.z * gv.z > thr) ? 0.0f : fv.z;
        o.w = (fv.w * gv.w > thr) ? 0.0f : fv.w;
        out[base + i] = o;
    }
}

__global__ void apply_tail_kernel(const float4* __restrict__ f, const float4* __restrict__ g,
                                  const float* __restrict__ thrF,
                                  float4* __restrict__ out, int tailCut) {
    const float thr = thrF[NS - 1];
    asm volatile("" :: "v"(thr));   // latch before overwriting the smalls region
    __syncthreads();
    const size_t base = (size_t)NS * NPSV - tailCut;
    for (int i = threadIdx.x; i < tailCut; i += 256) {
        const float4 fv = f[base + i];
        const float4 gv = g[base + i];
        float4 o;
        o.x = (fv.x * gv.x > thr) ? 0.0f : fv.x;
        o.y = (fv.y * gv.y > thr) ? 0.0f : fv.y;
        o.z = (fv.z * gv.z > thr) ? 0.0f : fv.z;
        o.w = (fv.w * gv.w > thr) ? 0.0f : fv.w;
        out[base + i] = o;
    }
}

extern "C" void kernel_launch(void* const* d_in, const int* in_sizes, int n_in,
                              void* d_out, int out_size, void* d_ws, size_t ws_size,
                              hipStream_t stream) {
    const float* f = (const float*)d_in[0];
    const float* g = (const float*)d_in[1];
    float* out = (float*)d_out;

    const size_t pairU32  = (size_t)NS * GX * PAIRCAP;                       // 2,097,152
    const size_t brBytes  = (size_t)NS * BRB * NB * sizeof(unsigned short);  // 8 MB
    const size_t bigBytes = (pairU32 * 8 > brBytes) ? pairU32 * 8 : brBytes; // 16.78 MB
    const size_t smallU32 = 2 * NS + NS * GXF + NS * GXF + 1 + NS;
    const size_t need     = bigBytes + smallU32 * 4;

    if (ws_size >= need) {
        // ---- tier-1 fast path: bracket hists and pairs share (time-disjoint) ws ----
        char* w = (char*)d_ws;
        unsigned short* bh = (unsigned short*)w;
        unsigned* pv   = (unsigned*)w;
        unsigned* ppos = pv + pairU32;
        unsigned* sm   = (unsigned*)(w + bigBytes);
        unsigned* binLU = sm;                  // 128
        unsigned* cnts  = binLU + 2 * NS;      // NS*GXF (fallback-sized, main uses NS*GX)
        unsigned* chis  = cnts + NS * GXF;
        unsigned* fail  = chis + NS * GXF;     // 1
        float*    thrF  = (float*)(fail + 1);  // 64

        bracket_kernel<<<dim3(BRB, NS), 256, 0, stream>>>((const float4*)f, (const float4*)g,
                                                          bh, fail);
        bracket_scan_kernel<<<NS, 256, 0, stream>>>(bh, binLU);
        scatter0_kernel<<<dim3(GX, NS), 256, 0, stream>>>((const float4*)f, (const float4*)g,
                                                          (float4*)out, pv, ppos, binLU,
                                                          cnts, chis, fail);
        select0_kernel<<<NS, 256, 0, stream>>>(pv, ppos, binLU, cnts, chis, fail, thrF, out);
        // guaranteed-exact fallback; all three no-op unless fail was set
        scatter_fb_kernel<<<dim3(GXF, NS), 256, 0, stream>>>((const float4*)f, (const float4*)g,
                                                             (unsigned*)out, cnts, chis, fail,
                                                             1, SEGF);
        select_fb_kernel<<<NS, 256, 0, stream>>>((const unsigned*)out, cnts, fail, thrF, 1);
        apply_fb_kernel<<<dim3(GXA, NS), 256, 0, stream>>>((const float4*)f, (const float4*)g,
                                                           thrF, (float4*)out, fail, 1, 0);
    } else {
        // ---- tier-2: no usable ws; everything lives in d_out (always exact for this
        // data: per-block positives ~12.5K << SEGCAP2) ----
        unsigned* list = (unsigned*)out;
        unsigned* sm   = (unsigned*)out + ((size_t)NS * NPS - 4 * TAILF4);
        unsigned* cnts = sm;
        unsigned* chis = cnts + NS * GXF;
        unsigned* fail = chis + NS * GXF;
        float*    thrF = (float*)(fail + 1);

        scatter_fb_kernel<<<dim3(GXF, NS), 256, 0, stream>>>((const float4*)f, (const float4*)g,
                                                             list, cnts, chis, fail, 2, SEGCAP2);
        select_fb_kernel<<<NS, 256, 0, stream>>>(list, cnts, fail, thrF, 2);
        apply_fb_kernel<<<dim3(GXA, NS), 256, 0, stream>>>((const float4*)f, (const float4*)g,
                                                           thrF, (float4*)out, fail, 2, TAILF4);
        apply_tail_kernel<<<1, 256, 0, stream>>>((const float4*)f, (const float4*)g,
                                                 thrF, (float4*)out, TAILF4);
    }
}